// Round 10
// baseline (1147.523 us; speedup 1.0000x reference)
//
#include <hip/hip_runtime.h>
#include <stdint.h>

using f32x4  = __attribute__((ext_vector_type(4))) float;
using bf16x8 = __attribute__((ext_vector_type(8))) __bf16;

#define GLOAD_LDS16(src, dst) __builtin_amdgcn_global_load_lds(                 \
    (const __attribute__((address_space(1))) void*)(src),                      \
    (__attribute__((address_space(3))) void*)(dst), 16, 0, 0)

// ===========================================================================
// Fragment-major, HALF-CONTIGUOUS layout (A and B identical family now):
//   128x128 bf16 tile, frag f = mi*4 + ks (mi=row/16, ks=k/32), lane
//   (l15,lq) holds T[mi*16+l15][ks*32+lq*8 ..+8] (16B = one ROW's 8 elems).
//   Storage slot order: half h = ks>>1 (1024 slots), then p = g*64 + lane,
//   g = mi*2 + (ks&1). Each staged 16B slot is a single row -> the e-scale
//   during staging is ONE broadcast multiply per slot.
// ===========================================================================

// x (fp32, row-major N x 256) -> actA half-contiguous frag-major bf16
__global__ void cvt_x_kernel(const float* __restrict__ x, __bf16* __restrict__ out) {
    const int u    = blockIdx.x * 256 + threadIdx.x;
    const int lane = u & 63;
    const int g    = (u >> 6) & 15;
    const int h    = (u >> 10) & 1;
    const int c    = (u >> 11) & 1;
    const int rb   = u >> 12;
    const int mi   = g >> 1;
    const int ks   = (h << 1) + (g & 1);
    const int row  = rb * 128 + mi * 16 + (lane & 15);
    const int i    = c * 128 + ks * 32 + ((lane >> 4) << 3);
    const float4 a = *(const float4*)(x + (size_t)row * 256 + i);
    const float4 b = *(const float4*)(x + (size_t)row * 256 + i + 4);
    bf16x8 pv;
    pv[0] = (__bf16)a.x; pv[1] = (__bf16)a.y; pv[2] = (__bf16)a.z; pv[3] = (__bf16)a.w;
    pv[4] = (__bf16)b.x; pv[5] = (__bf16)b.y; pv[6] = (__bf16)b.z; pv[7] = (__bf16)b.w;
    *(bf16x8*)(out + (size_t)u * 8) = pv;
}

// W (R x O x I fp32) -> Bt frag-major bf16, half-contiguous unit order.
template<int I, int O>
__global__ void prep_w_kernel(const float* __restrict__ W, __bf16* __restrict__ Bt) {
    constexpr int NCH = I >> 7;
    const int u    = blockIdx.x * 256 + threadIdx.x;     // < NCH*2048
    const int r    = blockIdx.y;
    const int nb   = blockIdx.z;
    const int lane = u & 63;
    const int g    = (u >> 6) & 15;
    const int h    = (u >> 10) & 1;
    const int c    = u >> 11;
    const int mi   = g >> 1;
    const int ks   = (h << 1) + (g & 1);
    const int row  = nb * 128 + mi * 16 + (lane & 15);
    const int i    = c * 128 + ks * 32 + ((lane >> 4) << 3);
    const float* src = W + ((size_t)r * O + row) * I + i;
    const float4 a = *(const float4*)src;
    const float4 b = *(const float4*)(src + 4);
    bf16x8 pv;
    pv[0] = (__bf16)a.x; pv[1] = (__bf16)a.y; pv[2] = (__bf16)a.z; pv[3] = (__bf16)a.w;
    pv[4] = (__bf16)b.x; pv[5] = (__bf16)b.y; pv[6] = (__bf16)b.z; pv[7] = (__bf16)b.w;
    *(bf16x8*)(Bt + ((((size_t)nb * 9 + r) * NCH + c) * 2048 + (u & 2047)) * 8) = pv;
}

// bias tiles: per nb one 128x64 tile, 16 frags (f = ni*2 + ks2)
template<int O>
__global__ void prep_bias_kernel(const float* __restrict__ b, __bf16* __restrict__ BtB) {
    const int u    = blockIdx.x * 256 + threadIdx.x;     // < (O/128)*1024
    const int nb   = u >> 10;
    const int q    = u & 1023;
    const int lane = q & 63;
    const int f    = q >> 6;
    const int row  = nb * 128 + ((f >> 1) << 4) + (lane & 15);
    const int kb   = ((f & 1) << 5) + ((lane >> 4) << 3);
    bf16x8 pv;
#pragma unroll
    for (int e = 0; e < 8; ++e) {
        const int k = kb + e;
        pv[e] = (k < 9) ? (__bf16)b[(size_t)k * O + row] : (__bf16)0.f;
    }
    *(bf16x8*)(BtB + (size_t)u * 8) = pv;
}

// ---------------------------------------------------------------------------
// Relation-mixed GEMM, e-scale folded into A-staging; acc is a PURE MFMA
// accumulator (no VALU touches until epilogue -> zero accvgpr traffic):
//   y[n,o] = sum_k u[n,k] Bt[o,k],  u[n, rI+i] = e[n,r] x[n,i]  (+ bias step)
// Per 128-col i-chunk: A-chunk held unscaled in 32 VGPR (8 coalesced loads).
// 18 phases s=2r+h. Phase: vmcnt(4) -> bar#1 [A(s),B(s) public] -> read
// av/bv -> lgkm0 -> bar#2 [bufs free] -> {DMA B(s+2); scale+ds_write A(r+1,h)
// (one e-broadcast mul per 16B slot)} -> 32 MFMA chained into acc.
// A ring-2 / B ring-2 by h. 128x128 tile, 4 waves.
// ---------------------------------------------------------------------------
template<int I, int O, bool RELU, bool OUTF32>
__global__ __launch_bounds__(256, 2)
void kg_gemm(const __bf16* __restrict__ A, const float* __restrict__ E,
             const __bf16* __restrict__ Bt, const __bf16* __restrict__ BtB,
             void* __restrict__ Outv) {
    constexpr int NCH = I >> 7;
    constexpr int NBN = O >> 7;
    static_assert((I & 127) == 0 && (O & 127) == 0, "tile divisibility");

    __shared__ __align__(16) char lds[65536 + 4608];
    // ldsA[h] = lds + h*16K ; ldsB[h] = lds + 32K + h*16K ; ldsE at 64K
    float* const ldsE = (float*)(lds + 65536);

    const int tid  = threadIdx.x;
    const int nwg  = gridDim.x;
    const int braw = blockIdx.x;
    const int bid  = (braw & 7) * (nwg >> 3) + (braw >> 3);   // XCD swizzle (nwg%8==0)
    const int rb   = bid / NBN;
    const int nb   = bid % NBN;
    const int bm0  = rb << 7;
    const int bn0  = nb << 7;
    const int lane = tid & 63;
    const int wid  = tid >> 6;
    const int wr   = (wid >> 1) << 6;
    const int wc   = (wid & 1) << 6;
    const int l15  = lane & 15;
    const int lq   = lane >> 4;

    if (tid < 128) {
        const float* e = E + (size_t)(bm0 + tid) * 9;
#pragma unroll
        for (int q = 0; q < 9; ++q) ldsE[q * 128 + tid] = e[q];
    }
    asm volatile("s_waitcnt lgkmcnt(0)" ::: "memory");
    __builtin_amdgcn_s_barrier();            // publish ldsE

    f32x4 acc[4][4];
#pragma unroll
    for (int m = 0; m < 4; ++m)
#pragma unroll
        for (int n = 0; n < 4; ++n)
            acc[m][n] = f32x4{0.f, 0.f, 0.f, 0.f};

    const size_t Bbase = (size_t)nb * 9 * NCH * 2048;   // units
    const int arow = wr >> 4;   // wave A mi base
    const int nfb  = wc >> 4;   // wave B ni base

    // staging row per slot-it: slot = it*256+tid -> g = it*4+(tid>>6),
    // mi = g>>1 = it*2+(tid>>7), row = mi*16 + (tid&15)
    int rowS[4];
#pragma unroll
    for (int it = 0; it < 4; ++it)
        rowS[it] = ((it * 2 + (tid >> 7)) << 4) + (tid & 15);

    auto stageB = [&](int s, int c) {   // B(s) -> ldsB[s&1]
        const __bf16* src = Bt + (Bbase + ((size_t)(s >> 1) * NCH + c) * 2048
                                  + (size_t)((s & 1) << 10)) * 8;
        char* dst = lds + 32768 + ((s & 1) << 14);
#pragma unroll
        for (int it = 0; it < 4; ++it) {
            const int q = it * 256 + tid;
            GLOAD_LDS16(src + (size_t)q * 8, dst + q * 16);
        }
    };

    bf16x8 ar[2][4];   // unscaled A chunk (both halves), 32 VGPR

    // scale+write A(rp, h) into ldsA[h]; ONE e broadcast per 16B slot
    auto scaleA = [&](const bf16x8* arh, int rp, int h) {
        char* dst = lds + (h << 14);
#pragma unroll
        for (int it = 0; it < 4; ++it) {
            const float ev = ldsE[rp * 128 + rowS[it]];
            bf16x8 pv;
#pragma unroll
            for (int e = 0; e < 8; ++e)
                pv[e] = (__bf16)((float)arh[it][e] * ev);
            *(bf16x8*)(dst + (it * 256 + tid) * 16) = pv;
        }
    };

#pragma unroll 1
    for (int c = 0; c < NCH; ++c) {
        // ---- chunk top: A-chunk regs (8 oldest vm ops) + B(0),B(1) DMA
        const __bf16* Ab = A + (size_t)(rb * NCH + c) * 2048 * 8;
#pragma unroll
        for (int h = 0; h < 2; ++h)
#pragma unroll
            for (int it = 0; it < 4; ++it)
                ar[h][it] = *(const bf16x8*)(Ab + ((size_t)((h << 10) + it * 256 + tid)) * 8);
        stageB(0, c); stageB(1, c);
        asm volatile("s_waitcnt vmcnt(8)" ::: "memory");   // A regs ready
        scaleA(ar[0], 0, 0);
        scaleA(ar[1], 0, 1);
        asm volatile("s_waitcnt lgkmcnt(0)" ::: "memory"); // drain A writes
        __builtin_amdgcn_sched_barrier(0);

#pragma unroll 1
        for (int r = 0; r < 9; ++r) {
#pragma unroll
            for (int h = 0; h < 2; ++h) {
                // ---- phase top: B(s) DMA complete (A(s) drained earlier)
                if (r == 8 && h == 1) asm volatile("s_waitcnt vmcnt(0)" ::: "memory");
                else                  asm volatile("s_waitcnt vmcnt(4)" ::: "memory");
                __builtin_amdgcn_s_barrier();              // #1: A(s),B(s) public
                __builtin_amdgcn_sched_barrier(0);
                const char* ap = lds + (h << 14);
                const char* bp = lds + 32768 + (h << 14);
                bf16x8 av[4][2], bv[4][2];
#pragma unroll
                for (int m = 0; m < 4; ++m)
#pragma unroll
                    for (int j = 0; j < 2; ++j)
                        av[m][j] = *(const bf16x8*)(ap + ((((arow + m) * 2 + j) << 6) + lane) * 16);
#pragma unroll
                for (int n = 0; n < 4; ++n)
#pragma unroll
                    for (int j = 0; j < 2; ++j)
                        bv[n][j] = *(const bf16x8*)(bp + ((((nfb + n) * 2 + j) << 6) + lane) * 16);
                asm volatile("s_waitcnt lgkmcnt(0)" ::: "memory");
                __builtin_amdgcn_sched_barrier(0);
                __builtin_amdgcn_s_barrier();              // #2: bufs reusable
                __builtin_amdgcn_sched_barrier(0);
                if (r < 8) {
                    stageB(2 * (r + 1) + h, c);            // B(s+2) -> ldsB[h]
                    scaleA(ar[h], r + 1, h);               // A(r+1,h) -> ldsA[h]
                }
                __builtin_amdgcn_s_setprio(1);
#pragma unroll
                for (int j = 0; j < 2; ++j)
#pragma unroll
                    for (int m = 0; m < 4; ++m)
#pragma unroll
                        for (int n = 0; n < 4; ++n)
                            acc[m][n] = __builtin_amdgcn_mfma_f32_16x16x32_bf16(
                                av[m][j], bv[n][j], acc[m][n], 0, 0, 0);
                __builtin_amdgcn_s_setprio(0);
            }
        }
    }

    // ---- bias K=64 step: A-cols = e (built from ldsE), B = BtB tile
    __syncthreads();   // full drain; guards buffer overwrite
    {
        char* const bufB = lds;            // 16 KB
        char* const bufA = lds + 16384;    // 16 KB
#pragma unroll
        for (int rr = 0; rr < 4; ++rr) {
            const int q = rr * 256 + tid;
            GLOAD_LDS16(BtB + ((size_t)nb * 1024 + q) * 8, bufB + q * 16);
        }
#pragma unroll
        for (int rr = 0; rr < 4; ++rr) {
            const int q    = rr * 256 + tid;
            const int ln   = q & 63;
            const int f    = q >> 6;                       // ni*2 + ks2
            const int row  = ((f >> 1) << 4) + (ln & 15);
            const int kb   = ((f & 1) << 5) + ((ln >> 4) << 3);
            bf16x8 pv;
#pragma unroll
            for (int e8 = 0; e8 < 8; ++e8) {
                const int k = kb + e8;
                pv[e8] = (k < 9) ? (__bf16)ldsE[k * 128 + row] : (__bf16)0.f;
            }
            *(bf16x8*)(bufA + q * 16) = pv;
        }
        __syncthreads();
#pragma unroll
        for (int ks = 0; ks < 2; ++ks) {
            bf16x8 av[4], bv[4];
#pragma unroll
            for (int m = 0; m < 4; ++m)
                av[m] = *(const bf16x8*)(bufA + (((((wr >> 4) + m) * 2 + ks) << 6) + lane) * 16);
#pragma unroll
            for (int n = 0; n < 4; ++n)
                bv[n] = *(const bf16x8*)(bufB + (((((wc >> 4) + n) * 2 + ks) << 6) + lane) * 16);
#pragma unroll
            for (int m = 0; m < 4; ++m)
#pragma unroll
                for (int n = 0; n < 4; ++n)
                    acc[m][n] = __builtin_amdgcn_mfma_f32_16x16x32_bf16(
                        av[m], bv[n], acc[m][n], 0, 0, 0);
        }
    }

    // ---- epilogue: C/D layout col = l15, row = lq*4 + j
    if (OUTF32) {
        const int orow0 = bm0 + wr + lq * 4;
        const int ocol0 = bn0 + wc + l15;
#pragma unroll
        for (int m = 0; m < 4; ++m)
#pragma unroll
            for (int n = 0; n < 4; ++n)
#pragma unroll
                for (int j = 0; j < 4; ++j) {
                    float v = acc[m][n][j];
                    if (RELU) v = fmaxf(v, 0.f);
                    ((float*)Outv)[(size_t)(orow0 + m * 16 + j) * O + (ocol0 + n * 16)] = v;
                }
    } else {
        // write next layer's A in half-contiguous frag-major (I' = O)
        constexpr int NCHn = O >> 7;
        __bf16* outp = (__bf16*)Outv;
#pragma unroll
        for (int m = 0; m < 4; ++m) {
#pragma unroll
            for (int n = 0; n < 4; ++n) {
                const int col  = bn0 + wc + n * 16 + l15;
                const int c2   = col >> 7;
                const int ks2  = (col >> 5) & 3;
                const int mi2  = (wr >> 4) + m;
                const int g2   = mi2 * 2 + (ks2 & 1);
                const int ln2  = ((col >> 3) & 3) * 16 + lq * 4;
                const size_t base =
                    (((size_t)(rb * NCHn + c2) * 2048) + ((size_t)(ks2 >> 1) << 10)
                     + g2 * 64 + ln2) * 8 + (col & 7);
#pragma unroll
                for (int j = 0; j < 4; ++j) {
                    float v = acc[m][n][j];
                    if (RELU) v = fmaxf(v, 0.f);
                    outp[base + (size_t)j * 8] = (__bf16)v;
                }
            }
        }
    }
}

// ---------------------------------------------------------------------------
extern "C" void kernel_launch(void* const* d_in, const int* in_sizes, int n_in,
                              void* d_out, int out_size, void* d_ws, size_t ws_size,
                              hipStream_t stream) {
    const float* x  = (const float*)d_in[0];
    const float* E  = (const float*)d_in[1];
    const float* W0 = (const float*)d_in[2];
    const float* b0 = (const float*)d_in[3];
    const float* W1 = (const float*)d_in[4];
    const float* b1 = (const float*)d_in[5];
    const float* W2 = (const float*)d_in[6];
    const float* b2 = (const float*)d_in[7];
    const float* W3 = (const float*)d_in[8];
    const float* b3 = (const float*)d_in[9];

    char* ws = (char*)d_ws;
    const size_t actBytes = (size_t)65536 * 512 * 2;           // 64 MiB each
    __bf16* actA = (__bf16*)ws;
    __bf16* actB = (__bf16*)(ws + actBytes);
    char* p = ws + 2 * actBytes;
    __bf16* Bt0 = (__bf16*)p; p += (size_t)4 * 9 * 2 * 2048 * 16;
    __bf16* Bt1 = (__bf16*)p; p += (size_t)4 * 9 * 4 * 2048 * 16;
    __bf16* Bt2 = (__bf16*)p; p += (size_t)4 * 9 * 4 * 2048 * 16;
    __bf16* Bt3 = (__bf16*)p; p += (size_t)2 * 9 * 4 * 2048 * 16;
    __bf16* BtB0 = (__bf16*)p; p += (size_t)4 * 1024 * 16;
    __bf16* BtB1 = (__bf16*)p; p += (size_t)4 * 1024 * 16;
    __bf16* BtB2 = (__bf16*)p; p += (size_t)4 * 1024 * 16;
    __bf16* BtB3 = (__bf16*)p; p += (size_t)2 * 1024 * 16;
    if (ws_size < (size_t)(p - ws)) return;   // ws too small -> visible failure

    // prep (all half-contiguous frag-major)
    cvt_x_kernel<<<dim3(8192), dim3(256), 0, stream>>>(x, actA);
    prep_w_kernel<256, 512><<<dim3(16, 9, 4), dim3(256), 0, stream>>>(W0, Bt0);
    prep_w_kernel<512, 512><<<dim3(32, 9, 4), dim3(256), 0, stream>>>(W1, Bt1);
    prep_w_kernel<512, 512><<<dim3(32, 9, 4), dim3(256), 0, stream>>>(W2, Bt2);
    prep_w_kernel<512, 256><<<dim3(32, 9, 2), dim3(256), 0, stream>>>(W3, Bt3);
    prep_bias_kernel<512><<<dim3(16), dim3(256), 0, stream>>>(b0, BtB0);
    prep_bias_kernel<512><<<dim3(16), dim3(256), 0, stream>>>(b1, BtB1);
    prep_bias_kernel<512><<<dim3(16), dim3(256), 0, stream>>>(b2, BtB2);
    prep_bias_kernel<256><<<dim3(8),  dim3(256), 0, stream>>>(b3, BtB3);

    // 4 fused layers
    kg_gemm<256, 512, true,  false><<<dim3(2048), dim3(256), 0, stream>>>(actA, E, Bt0, BtB0, actB);
    kg_gemm<512, 512, true,  false><<<dim3(2048), dim3(256), 0, stream>>>(actB, E, Bt1, BtB1, actA);
    kg_gemm<512, 512, true,  false><<<dim3(2048), dim3(256), 0, stream>>>(actA, E, Bt2, BtB2, actB);
    kg_gemm<512, 256, false, true ><<<dim3(1024), dim3(256), 0, stream>>>(actB, E, Bt3, BtB3, d_out);
}